// Round 1
// baseline (1820.452 us; speedup 1.0000x reference)
//
#include <hip/hip_runtime.h>

#define HH 256

constexpr int NB   = 16;
constexpr int T0   = 4096;
constexpr int FDIM = 1024;
constexpr int R0   = NB * T0;   // 65536
constexpr int R1   = R0 / 2;    // 32768
constexpr int R2   = R0 / 4;    // 16384
constexpr int R3   = R0 / 8;    // 8192

__device__ __forceinline__ void load8f(const float* __restrict__ p, float f[8]) {
    float4 a = *reinterpret_cast<const float4*>(p);
    float4 b = *reinterpret_cast<const float4*>(p + 4);
    f[0]=a.x; f[1]=a.y; f[2]=a.z; f[3]=a.w;
    f[4]=b.x; f[5]=b.y; f[6]=b.z; f[7]=b.w;
}

// C = A @ Bself [+ nbr_mean(A) @ Bnbr] + bias, optional leaky.
// A: R x K row-major (K = row stride). B: K x 256 row-major. out: R x 256.
// Tiles: 128x128x16, 256 threads, 8x8 microtile.
template<int HAS_NBR, int LEAKY>
__launch_bounds__(256)
__global__ void gemm_kernel(const float* __restrict__ A,
                            const float* __restrict__ Bself,
                            const float* __restrict__ Bnbr,
                            const float* __restrict__ bias,
                            float* __restrict__ out,
                            int K, int Tl)
{
    __shared__ float As[16][132];   // k-major, padded
    __shared__ float Bs[16][128];

    const int tid = threadIdx.x;
    const int tx  = tid & 15;
    const int ty  = tid >> 4;
    const size_t row0 = (size_t)blockIdx.x * 128;
    const int n0 = blockIdx.y * 128;

    const int a_r = tid >> 1;        // 0..127
    const int a_c = (tid & 1) * 8;   // 0 or 8
    const int b_r = tid >> 4;        // 0..15
    const int b_c = tx * 8;          // 0..120

    float acc[8][8];
#pragma unroll
    for (int i = 0; i < 8; i++)
#pragma unroll
        for (int j = 0; j < 8; j++) acc[i][j] = 0.f;

    const size_t grow = row0 + a_r;

    // neighbor-mean validity for this thread's A row (only used when HAS_NBR)
    float invcnt = 1.f;
    int valid_mask = 0;
    if (HAS_NBR) {
        int t = (int)(grow & (size_t)(Tl - 1));
        int cnt = 0;
        const int offs[4] = {-2, -1, 1, 2};
#pragma unroll
        for (int oi = 0; oi < 4; ++oi) {
            int tn = t + offs[oi];
            if (tn >= 0 && tn < Tl) { valid_mask |= (1 << oi); cnt++; }
        }
        invcnt = 1.f / (float)cnt;
    }

#pragma unroll
    for (int seg = 0; seg < (HAS_NBR ? 2 : 1); ++seg) {
        const float* __restrict__ Bm = seg ? Bnbr : Bself;
        for (int k0 = 0; k0 < K; k0 += 16) {
            float av[8];
            if (seg == 0) {
                load8f(A + grow * (size_t)K + (k0 + a_c), av);
            } else {
                const int offs[4] = {-2, -1, 1, 2};
#pragma unroll
                for (int j = 0; j < 8; j++) av[j] = 0.f;
#pragma unroll
                for (int oi = 0; oi < 4; ++oi) {
                    if (valid_mask & (1 << oi)) {
                        float tmp[8];
                        load8f(A + (grow + offs[oi]) * (size_t)K + (k0 + a_c), tmp);
#pragma unroll
                        for (int j = 0; j < 8; j++) av[j] += tmp[j];
                    }
                }
#pragma unroll
                for (int j = 0; j < 8; j++) av[j] *= invcnt;
            }
#pragma unroll
            for (int j = 0; j < 8; j++) As[a_c + j][a_r] = av[j];

            float4 bv0 = *reinterpret_cast<const float4*>(Bm + (size_t)(k0 + b_r) * HH + n0 + b_c);
            float4 bv1 = *reinterpret_cast<const float4*>(Bm + (size_t)(k0 + b_r) * HH + n0 + b_c + 4);
            *reinterpret_cast<float4*>(&Bs[b_r][b_c])     = bv0;
            *reinterpret_cast<float4*>(&Bs[b_r][b_c + 4]) = bv1;

            __syncthreads();
#pragma unroll
            for (int k = 0; k < 16; k++) {
                float4 al = *reinterpret_cast<const float4*>(&As[k][ty * 8]);
                float4 ah = *reinterpret_cast<const float4*>(&As[k][ty * 8 + 4]);
                float4 bl = *reinterpret_cast<const float4*>(&Bs[k][tx * 8]);
                float4 bh = *reinterpret_cast<const float4*>(&Bs[k][tx * 8 + 4]);
                float a8[8] = {al.x, al.y, al.z, al.w, ah.x, ah.y, ah.z, ah.w};
                float b8[8] = {bl.x, bl.y, bl.z, bl.w, bh.x, bh.y, bh.z, bh.w};
#pragma unroll
                for (int i = 0; i < 8; i++)
#pragma unroll
                    for (int j = 0; j < 8; j++)
                        acc[i][j] = fmaf(a8[i], b8[j], acc[i][j]);
            }
            __syncthreads();
        }
    }

    float bb[8];
#pragma unroll
    for (int j = 0; j < 8; j++) bb[j] = bias[n0 + tx * 8 + j];

#pragma unroll
    for (int i = 0; i < 8; i++) {
        size_t row = row0 + ty * 8 + i;
        float v[8];
#pragma unroll
        for (int j = 0; j < 8; j++) {
            float t = acc[i][j] + bb[j];
            if (LEAKY) t = (t >= 0.f) ? t : 0.2f * t;
            v[j] = t;
        }
        float* o = out + row * HH + n0 + tx * 8;
        *reinterpret_cast<float4*>(o)     = make_float4(v[0], v[1], v[2], v[3]);
        *reinterpret_cast<float4*>(o + 4) = make_float4(v[4], v[5], v[6], v[7]);
    }
}

// out[r] = in[2r]  (strided 2x downsample along time)
__global__ void downsample_kernel(const float* __restrict__ in, float* __restrict__ out, int Rout)
{
    int idx = blockIdx.x * blockDim.x + threadIdx.x;
    int r  = idx >> 6;
    int h0 = (idx & 63) * 4;
    if (r >= Rout) return;
    *reinterpret_cast<float4*>(out + (size_t)r * HH + h0) =
        *reinterpret_cast<const float4*>(in + (size_t)(2 * r) * HH + h0);
}

// res[r] += upsample2(c)[r], in place on res. Tc = coarse T, Tl = 2*Tc, tlshift = log2(Tl)
__global__ void upsample_add_kernel(float* __restrict__ res, const float* __restrict__ c,
                                    int Tc, int tlshift, int Rout)
{
    int idx = blockIdx.x * blockDim.x + threadIdx.x;
    int r  = idx >> 6;
    int h0 = (idx & 63) * 4;
    if (r >= Rout) return;
    int Tl = Tc * 2;
    int t  = r & (Tl - 1);
    int bq = r >> tlshift;
    int k  = t >> 1;
    size_t rc = (size_t)bq * Tc + k;
    float4 u;
    if ((t & 1) == 0) {
        u = *reinterpret_cast<const float4*>(c + rc * HH + h0);
    } else if (k < Tc - 1) {
        float4 u0 = *reinterpret_cast<const float4*>(c + rc * HH + h0);
        float4 u1 = *reinterpret_cast<const float4*>(c + (rc + 1) * HH + h0);
        u = make_float4(0.5f * (u0.x + u1.x), 0.5f * (u0.y + u1.y),
                        0.5f * (u0.z + u1.z), 0.5f * (u0.w + u1.w));
    } else {
        float4 u0 = *reinterpret_cast<const float4*>(c + rc * HH + h0);
        float4 um = *reinterpret_cast<const float4*>(c + (rc - 1) * HH + h0);
        u = make_float4(0.9f * u0.x + 0.1f * um.x, 0.9f * u0.y + 0.1f * um.y,
                        0.9f * u0.z + 0.1f * um.z, 0.9f * u0.w + 0.1f * um.w);
    }
    float* rp = res + (size_t)r * HH + h0;
    float4 rv = *reinterpret_cast<const float4*>(rp);
    *reinterpret_cast<float4*>(rp) = make_float4(rv.x + u.x, rv.y + u.y, rv.z + u.z, rv.w + u.w);
}

// dst[r] = (RESID ? dst[r] : 0) + leaky(layernorm(src[r]) * g + b). One wave per row.
template<int RESID>
__launch_bounds__(64)
__global__ void ln_kernel(const float* __restrict__ src, float* __restrict__ dst,
                          const float* __restrict__ g, const float* __restrict__ b)
{
    const size_t r = blockIdx.x;
    const int lane = threadIdx.x;
    const float* row = src + r * HH;
    float4 xv = *reinterpret_cast<const float4*>(row + lane * 4);
    float x0 = xv.x, x1 = xv.y, x2 = xv.z, x3 = xv.w;

    float s = x0 + x1 + x2 + x3;
#pragma unroll
    for (int off = 32; off >= 1; off >>= 1) s += __shfl_xor(s, off);
    float mu = s * (1.0f / HH);

    float d0 = x0 - mu, d1 = x1 - mu, d2 = x2 - mu, d3 = x3 - mu;
    float vs = d0 * d0 + d1 * d1 + d2 * d2 + d3 * d3;
#pragma unroll
    for (int off = 32; off >= 1; off >>= 1) vs += __shfl_xor(vs, off);
    float inv = rsqrtf(vs * (1.0f / HH) + 1e-5f);

    float4 gv = *reinterpret_cast<const float4*>(g + lane * 4);
    float4 bv = *reinterpret_cast<const float4*>(b + lane * 4);
    float y0 = d0 * inv * gv.x + bv.x;
    float y1 = d1 * inv * gv.y + bv.y;
    float y2 = d2 * inv * gv.z + bv.z;
    float y3 = d3 * inv * gv.w + bv.w;
    y0 = (y0 >= 0.f) ? y0 : 0.2f * y0;
    y1 = (y1 >= 0.f) ? y1 : 0.2f * y1;
    y2 = (y2 >= 0.f) ? y2 : 0.2f * y2;
    y3 = (y3 >= 0.f) ? y3 : 0.2f * y3;

    float* dp = dst + r * HH + lane * 4;
    if (RESID) {
        float4 rv = *reinterpret_cast<const float4*>(dp);
        y0 += rv.x; y1 += rv.y; y2 += rv.z; y3 += rv.w;
    }
    *reinterpret_cast<float4*>(dp) = make_float4(y0, y1, y2, y3);
}

static void run_stage(int s, int R, int Tl, float* c, bool residual, bool has_nbr,
                      float* t1, float* t2, float* final_out,
                      const float* Wself, const float* Wnbr,
                      const float* bconv, const float* ln_g, const float* ln_b,
                      hipStream_t stream)
{
    const float* Ws0 = Wself + (size_t)(s * 2 + 0) * HH * HH;
    const float* Ws1 = Wself + (size_t)(s * 2 + 1) * HH * HH;
    const float* Wn0 = Wnbr  + (size_t)(s * 2 + 0) * HH * HH;
    const float* Wn1 = Wnbr  + (size_t)(s * 2 + 1) * HH * HH;
    const float* bc0 = bconv + (s * 2 + 0) * HH;
    const float* bc1 = bconv + (s * 2 + 1) * HH;

    dim3 grid(R / 128, HH / 128);
    if (has_nbr) {
        gemm_kernel<1, 1><<<grid, 256, 0, stream>>>(c,  Ws0, Wn0, bc0, t1, HH, Tl);
        gemm_kernel<1, 0><<<grid, 256, 0, stream>>>(t1, Ws1, Wn1, bc1, t2, HH, Tl);
    } else {
        gemm_kernel<0, 1><<<grid, 256, 0, stream>>>(c,  Ws0, nullptr, bc0, t1, HH, Tl);
        gemm_kernel<0, 0><<<grid, 256, 0, stream>>>(t1, Ws1, nullptr, bc1, t2, HH, Tl);
    }
    const float* g  = ln_g + s * HH;
    const float* bb = ln_b + s * HH;
    if (final_out)     ln_kernel<0><<<R, 64, 0, stream>>>(t2, final_out, g, bb);
    else if (residual) ln_kernel<1><<<R, 64, 0, stream>>>(t2, c, g, bb);
    else               ln_kernel<0><<<R, 64, 0, stream>>>(t2, c, g, bb);
}

extern "C" void kernel_launch(void* const* d_in, const int* in_sizes, int n_in,
                              void* d_out, int out_size, void* d_ws, size_t ws_size,
                              hipStream_t stream)
{
    const float* x     = (const float*)d_in[0];
    const float* Wp    = (const float*)d_in[6];
    const float* bp    = (const float*)d_in[7];
    const float* Wself = (const float*)d_in[8];
    const float* Wnbr  = (const float*)d_in[9];
    const float* bconv = (const float*)d_in[10];
    const float* ln_g  = (const float*)d_in[11];
    const float* ln_b  = (const float*)d_in[12];
    float* out = (float*)d_out;   // also serves as conv2 scratch (t2) for every stage

    char* p = (char*)d_ws;
    float* c0 = (float*)p; p += (size_t)R0 * HH * 4;   // 64 MiB (feat / skip0)
    float* c1 = (float*)p; p += (size_t)R1 * HH * 4;   // 32 MiB (skip1)
    float* c2 = (float*)p; p += (size_t)R2 * HH * 4;   // 16 MiB (skip2)
    float* c3 = (float*)p; p += (size_t)R3 * HH * 4;   //  8 MiB
    float* t1 = (float*)p; p += (size_t)R0 * HH * 4;   // 64 MiB (conv1 temp)
    size_t needed = (size_t)(p - (char*)d_ws);
    if (ws_size < needed) return;  // workspace too small: bail (will fail loudly)

    // 1. projection: c0 = x @ Wp + bp   (65536 x 1024 @ 1024 x 256)
    gemm_kernel<0, 0><<<dim3(R0 / 128, HH / 128), 256, 0, stream>>>(
        x, Wp, nullptr, bp, c0, FDIM, 0);

    // 2. down path (residual stages, WIN neighbors)
    downsample_kernel<<<R1 / 4, 256, 0, stream>>>(c0, c1, R1);
    run_stage(0, R1, 2048, c1, true, true, t1, out, nullptr, Wself, Wnbr, bconv, ln_g, ln_b, stream);

    downsample_kernel<<<R2 / 4, 256, 0, stream>>>(c1, c2, R2);
    run_stage(1, R2, 1024, c2, true, true, t1, out, nullptr, Wself, Wnbr, bconv, ln_g, ln_b, stream);

    downsample_kernel<<<R3 / 4, 256, 0, stream>>>(c2, c3, R3);
    run_stage(2, R3, 512, c3, true, true, t1, out, nullptr, Wself, Wnbr, bconv, ln_g, ln_b, stream);

    // 3. up path (no residual; nbr only on the last stage)
    upsample_add_kernel<<<R2 / 4, 256, 0, stream>>>(c2, c3, 512, 10, R2);
    run_stage(3, R2, 1024, c2, false, false, t1, out, nullptr, Wself, Wnbr, bconv, ln_g, ln_b, stream);

    upsample_add_kernel<<<R1 / 4, 256, 0, stream>>>(c1, c2, 1024, 11, R1);
    run_stage(4, R1, 2048, c1, false, false, t1, out, nullptr, Wself, Wnbr, bconv, ln_g, ln_b, stream);

    upsample_add_kernel<<<R0 / 4, 256, 0, stream>>>(c0, c1, 2048, 12, R0);
    run_stage(5, R0, 4096, c0, false, true, t1, out, out, Wself, Wnbr, bconv, ln_g, ln_b, stream);
}

// Round 2
// 511.486 us; speedup vs baseline: 3.5591x; 3.5591x over previous
//
#include <hip/hip_runtime.h>

#define HH 256

typedef __attribute__((ext_vector_type(8))) short short8;
typedef __attribute__((ext_vector_type(4))) float f32x4;
typedef __attribute__((ext_vector_type(4))) unsigned short u16x4;
typedef __attribute__((ext_vector_type(8))) unsigned short u16x8;

constexpr int NB   = 16;
constexpr int T0   = 4096;
constexpr int FDIM = 1024;
constexpr int R0   = NB * T0;   // 65536
constexpr int R1   = R0 / 2;    // 32768
constexpr int R2   = R0 / 4;    // 16384
constexpr int R3   = R0 / 8;    // 8192

__device__ __forceinline__ float b2f(unsigned short u) {
    union { unsigned int i; float f; } v; v.i = ((unsigned int)u) << 16; return v.f;
}
__device__ __forceinline__ unsigned short f2b(float f) {
    union { float f; unsigned int i; } v; v.f = f;
    unsigned int r = v.i + 0x7fffu + ((v.i >> 16) & 1u);
    return (unsigned short)(r >> 16);
}
__device__ __forceinline__ void gload16(const void* g, void* l) {
    __builtin_amdgcn_global_load_lds((const __attribute__((address_space(1))) void*)g,
                                     (__attribute__((address_space(3))) void*)l, 16, 0, 0);
}

// ---------------- weight transpose+convert: src fp32 [K][256] -> dst bf16 [256][K] ----------------
__global__ void transpose_w(const float* __restrict__ src, unsigned short* __restrict__ dst,
                            int K, int tilesPerMat)
{
    int bid = blockIdx.x;
    int m = bid / tilesPerMat;
    int t = bid % tilesPerMat;
    int tr = t >> 3, tc = t & 7;            // K/32 row-tiles, 8 col-tiles
    const float* S = src + (size_t)m * K * HH;
    unsigned short* D = dst + (size_t)m * HH * K;
    __shared__ float tile[32][33];
    int x = threadIdx.x & 31, y = threadIdx.x >> 5;
#pragma unroll
    for (int i = y; i < 32; i += 8)
        tile[i][x] = S[(size_t)(tr * 32 + i) * HH + tc * 32 + x];
    __syncthreads();
#pragma unroll
    for (int i = y; i < 32; i += 8)
        D[(size_t)(tc * 32 + i) * K + tr * 32 + x] = f2b(tile[x][i]);
}

// ---------------- bf16 MFMA GEMM: out[r][c] = sum_seg A_seg @ B_seg + bias ----------------
// A: R x 256 bf16 row-major. B: 256 x 256 bf16, stored [n][k]. 128x128 tile, 4 waves, 16x16x32.
template<int LEAKY>
__launch_bounds__(256)
__global__ void gemm_bf16(const unsigned short* __restrict__ A0, const unsigned short* __restrict__ B0,
                          const unsigned short* __restrict__ A1, const unsigned short* __restrict__ B1,
                          const float* __restrict__ bias, unsigned short* __restrict__ out,
                          int nseg)
{
    __shared__ unsigned short As[128 * 32];
    __shared__ unsigned short Bs[128 * 32];
    const int tid  = threadIdx.x;
    const int lane = tid & 63;
    const int w    = tid >> 6;
    const int wm   = w >> 1, wn = w & 1;
    const size_t row0 = (size_t)blockIdx.y * 128;
    const int n0 = blockIdx.x * 128;

    f32x4 acc[4][4] = {};

    for (int seg = 0; seg < nseg; ++seg) {
        const unsigned short* __restrict__ A = seg ? A1 : A0;
        const unsigned short* __restrict__ B = seg ? B1 : B0;
        for (int k0 = 0; k0 < HH; k0 += 32) {
#pragma unroll
            for (int i = 0; i < 2; i++) {
                int chunk = tid + 256 * i;
                int r = chunk >> 2, ks = chunk & 3;
                gload16(A + (row0 + r) * HH + k0 + ks * 8, &As[chunk * 8]);
                gload16(B + (size_t)(n0 + r) * HH + k0 + ks * 8, &Bs[chunk * 8]);
            }
            __syncthreads();
            short8 af[4], bg[4];
#pragma unroll
            for (int i = 0; i < 4; i++) {
                af[i] = *(const short8*)&As[(wm * 64 + i * 16 + (lane & 15)) * 32 + (lane >> 4) * 8];
                bg[i] = *(const short8*)&Bs[(wn * 64 + i * 16 + (lane & 15)) * 32 + (lane >> 4) * 8];
            }
#pragma unroll
            for (int mi = 0; mi < 4; mi++)
#pragma unroll
                for (int ni = 0; ni < 4; ni++)
                    acc[mi][ni] = __builtin_amdgcn_mfma_f32_16x16x32_bf16(af[mi], bg[ni], acc[mi][ni], 0, 0, 0);
            __syncthreads();
        }
    }

#pragma unroll
    for (int mi = 0; mi < 4; mi++) {
        size_t rbase = row0 + wm * 64 + mi * 16 + (lane >> 4) * 4;
#pragma unroll
        for (int ni = 0; ni < 4; ni++) {
            int c = n0 + wn * 64 + ni * 16 + (lane & 15);
            float bb = bias[c];
            f32x4 v = acc[mi][ni];
#pragma unroll
            for (int r = 0; r < 4; r++) {
                float t = v[r] + bb;
                if (LEAKY) t = (t >= 0.f) ? t : 0.2f * t;
                out[(rbase + r) * HH + c] = f2b(t);
            }
        }
    }
}

// ---------------- projection GEMM: A fp32 [R0][1024], B bf16 [256][1024], out bf16 ----------------
__launch_bounds__(256)
__global__ void proj_gemm(const float* __restrict__ A, const unsigned short* __restrict__ Bt,
                          const float* __restrict__ bias, unsigned short* __restrict__ out)
{
    __shared__ unsigned short As[128 * 32];
    __shared__ unsigned short Bs[128 * 32];
    const int tid  = threadIdx.x;
    const int lane = tid & 63;
    const int w    = tid >> 6;
    const int wm   = w >> 1, wn = w & 1;
    const size_t row0 = (size_t)blockIdx.y * 128;
    const int n0 = blockIdx.x * 128;

    f32x4 acc[4][4] = {};

    for (int k0 = 0; k0 < FDIM; k0 += 32) {
#pragma unroll
        for (int i = 0; i < 2; i++) {
            int chunk = tid + 256 * i;
            int r = chunk >> 2, ks = chunk & 3;
            gload16(Bt + (size_t)(n0 + r) * FDIM + k0 + ks * 8, &Bs[chunk * 8]);
        }
#pragma unroll
        for (int i = 0; i < 4; i++) {
            int chunk = tid + 256 * i;
            int r = chunk >> 3, fs = chunk & 7;
            float4 v = *(const float4*)(A + (row0 + r) * (size_t)FDIM + k0 + fs * 4);
            u16x4 u = { f2b(v.x), f2b(v.y), f2b(v.z), f2b(v.w) };
            *(u16x4*)&As[r * 32 + fs * 4] = u;
        }
        __syncthreads();
        short8 af[4], bg[4];
#pragma unroll
        for (int i = 0; i < 4; i++) {
            af[i] = *(const short8*)&As[(wm * 64 + i * 16 + (lane & 15)) * 32 + (lane >> 4) * 8];
            bg[i] = *(const short8*)&Bs[(wn * 64 + i * 16 + (lane & 15)) * 32 + (lane >> 4) * 8];
        }
#pragma unroll
        for (int mi = 0; mi < 4; mi++)
#pragma unroll
            for (int ni = 0; ni < 4; ni++)
                acc[mi][ni] = __builtin_amdgcn_mfma_f32_16x16x32_bf16(af[mi], bg[ni], acc[mi][ni], 0, 0, 0);
        __syncthreads();
    }

#pragma unroll
    for (int mi = 0; mi < 4; mi++) {
        size_t rbase = row0 + wm * 64 + mi * 16 + (lane >> 4) * 4;
#pragma unroll
        for (int ni = 0; ni < 4; ni++) {
            int c = n0 + wn * 64 + ni * 16 + (lane & 15);
            float bb = bias[c];
            f32x4 v = acc[mi][ni];
#pragma unroll
            for (int r = 0; r < 4; r++)
                out[(rbase + r) * HH + c] = f2b(v[r] + bb);
        }
    }
}

// ---------------- nbr mean (bf16): out[r] = mean of valid in[r+o], o in {-2,-1,1,2} ----------------
__global__ void nbr_kernel(const unsigned short* __restrict__ in, unsigned short* __restrict__ out,
                           int Tl, int R)
{
    int idx = blockIdx.x * 256 + threadIdx.x;
    int r = idx >> 5, cc = (idx & 31) * 8;
    if (r >= R) return;
    int t = r & (Tl - 1);
    float a[8] = {0, 0, 0, 0, 0, 0, 0, 0};
    int cnt = 0;
    const int offs[4] = {-2, -1, 1, 2};
#pragma unroll
    for (int oi = 0; oi < 4; ++oi) {
        int tn = t + offs[oi];
        if (tn >= 0 && tn < Tl) {
            cnt++;
            u16x8 v = *(const u16x8*)(in + (size_t)(r + offs[oi]) * HH + cc);
#pragma unroll
            for (int j = 0; j < 8; j++) a[j] += b2f(v[j]);
        }
    }
    float inv = 1.f / (float)cnt;
    u16x8 o;
#pragma unroll
    for (int j = 0; j < 8; j++) o[j] = f2b(a[j] * inv);
    *(u16x8*)(out + (size_t)r * HH + cc) = o;
}

// ---------------- downsample (bf16): out[r] = in[2r] ----------------
__global__ void downsample_kernel(const unsigned short* __restrict__ in,
                                  unsigned short* __restrict__ out, int Rout)
{
    int idx = blockIdx.x * 256 + threadIdx.x;
    int r = idx >> 5, cc = (idx & 31) * 8;
    if (r >= Rout) return;
    *(u16x8*)(out + (size_t)r * HH + cc) = *(const u16x8*)(in + (size_t)(2 * r) * HH + cc);
}

// ---------------- upsample + residual add (bf16), in place on res ----------------
__global__ void upsample_add_kernel(unsigned short* __restrict__ res, const unsigned short* __restrict__ c,
                                    int Tc, int tlshift, int Rout)
{
    int idx = blockIdx.x * 256 + threadIdx.x;
    int r = idx >> 5, cc = (idx & 31) * 8;
    if (r >= Rout) return;
    int Tl = Tc * 2;
    int t  = r & (Tl - 1);
    int bq = r >> tlshift;
    int k  = t >> 1;
    size_t rc = (size_t)bq * Tc + k;
    float u[8];
    if (!(t & 1)) {
        u16x8 v = *(const u16x8*)(c + rc * HH + cc);
#pragma unroll
        for (int j = 0; j < 8; j++) u[j] = b2f(v[j]);
    } else if (k < Tc - 1) {
        u16x8 v0 = *(const u16x8*)(c + rc * HH + cc);
        u16x8 v1 = *(const u16x8*)(c + (rc + 1) * HH + cc);
#pragma unroll
        for (int j = 0; j < 8; j++) u[j] = 0.5f * (b2f(v0[j]) + b2f(v1[j]));
    } else {
        u16x8 v0 = *(const u16x8*)(c + rc * HH + cc);
        u16x8 vm = *(const u16x8*)(c + (rc - 1) * HH + cc);
#pragma unroll
        for (int j = 0; j < 8; j++) u[j] = 0.9f * b2f(v0[j]) + 0.1f * b2f(vm[j]);
    }
    u16x8 rv = *(const u16x8*)(res + (size_t)r * HH + cc);
    u16x8 o;
#pragma unroll
    for (int j = 0; j < 8; j++) o[j] = f2b(b2f(rv[j]) + u[j]);
    *(u16x8*)(res + (size_t)r * HH + cc) = o;
}

// ---------------- LayerNorm + leaky; optional residual add; optional fp32 final out ----------------
// 4 rows per block (1 wave each).
template<int RESID, int F32OUT>
__launch_bounds__(256)
__global__ void ln_kernel(const unsigned short* __restrict__ src, void* __restrict__ dstv,
                          const float* __restrict__ g, const float* __restrict__ b)
{
    size_t row = (size_t)blockIdx.x * 4 + (threadIdx.x >> 6);
    int lane = threadIdx.x & 63;
    u16x4 xv = *(const u16x4*)(src + row * HH + lane * 4);
    float x0 = b2f(xv[0]), x1 = b2f(xv[1]), x2 = b2f(xv[2]), x3 = b2f(xv[3]);

    float s = x0 + x1 + x2 + x3;
#pragma unroll
    for (int off = 32; off >= 1; off >>= 1) s += __shfl_xor(s, off);
    float mu = s * (1.0f / HH);

    float d0 = x0 - mu, d1 = x1 - mu, d2 = x2 - mu, d3 = x3 - mu;
    float vs = d0 * d0 + d1 * d1 + d2 * d2 + d3 * d3;
#pragma unroll
    for (int off = 32; off >= 1; off >>= 1) vs += __shfl_xor(vs, off);
    float inv = rsqrtf(vs * (1.0f / HH) + 1e-5f);

    float4 gv = *reinterpret_cast<const float4*>(g + lane * 4);
    float4 bv = *reinterpret_cast<const float4*>(b + lane * 4);
    float y0 = d0 * inv * gv.x + bv.x;
    float y1 = d1 * inv * gv.y + bv.y;
    float y2 = d2 * inv * gv.z + bv.z;
    float y3 = d3 * inv * gv.w + bv.w;
    y0 = (y0 >= 0.f) ? y0 : 0.2f * y0;
    y1 = (y1 >= 0.f) ? y1 : 0.2f * y1;
    y2 = (y2 >= 0.f) ? y2 : 0.2f * y2;
    y3 = (y3 >= 0.f) ? y3 : 0.2f * y3;

    if (F32OUT) {
        float* d = (float*)dstv + row * HH + lane * 4;
        *reinterpret_cast<float4*>(d) = make_float4(y0, y1, y2, y3);
    } else {
        unsigned short* d = (unsigned short*)dstv + row * HH + lane * 4;
        if (RESID) {
            u16x4 rv = *(const u16x4*)d;
            y0 += b2f(rv[0]); y1 += b2f(rv[1]); y2 += b2f(rv[2]); y3 += b2f(rv[3]);
        }
        u16x4 o = { f2b(y0), f2b(y1), f2b(y2), f2b(y3) };
        *(u16x4*)d = o;
    }
}

static void run_stage(int s, int R, int Tl, unsigned short* c, bool residual, bool has_nbr,
                      unsigned short* t1, unsigned short* t2, unsigned short* nb, float* final_out,
                      const unsigned short* Wself_t, const unsigned short* Wnbr_t,
                      const float* bconv, const float* ln_g, const float* ln_b,
                      hipStream_t stream)
{
    const unsigned short* Ws0 = Wself_t + (size_t)(s * 2 + 0) * HH * HH;
    const unsigned short* Ws1 = Wself_t + (size_t)(s * 2 + 1) * HH * HH;
    const unsigned short* Wn0 = Wnbr_t  + (size_t)(s * 2 + 0) * HH * HH;
    const unsigned short* Wn1 = Wnbr_t  + (size_t)(s * 2 + 1) * HH * HH;
    const float* bc0 = bconv + (s * 2 + 0) * HH;
    const float* bc1 = bconv + (s * 2 + 1) * HH;

    dim3 grid(2, R / 128);
    if (has_nbr) {
        nbr_kernel<<<R / 8, 256, 0, stream>>>(c, nb, Tl, R);
        gemm_bf16<1><<<grid, 256, 0, stream>>>(c,  Ws0, nb, Wn0, bc0, t1, 2);
        nbr_kernel<<<R / 8, 256, 0, stream>>>(t1, nb, Tl, R);
        gemm_bf16<0><<<grid, 256, 0, stream>>>(t1, Ws1, nb, Wn1, bc1, t2, 2);
    } else {
        gemm_bf16<1><<<grid, 256, 0, stream>>>(c,  Ws0, nullptr, nullptr, bc0, t1, 1);
        gemm_bf16<0><<<grid, 256, 0, stream>>>(t1, Ws1, nullptr, nullptr, bc1, t2, 1);
    }
    const float* g  = ln_g + s * HH;
    const float* bb = ln_b + s * HH;
    if (final_out)     ln_kernel<0, 1><<<R / 4, 256, 0, stream>>>(t2, final_out, g, bb);
    else if (residual) ln_kernel<1, 0><<<R / 4, 256, 0, stream>>>(t2, c, g, bb);
    else               ln_kernel<0, 0><<<R / 4, 256, 0, stream>>>(t2, c, g, bb);
}

extern "C" void kernel_launch(void* const* d_in, const int* in_sizes, int n_in,
                              void* d_out, int out_size, void* d_ws, size_t ws_size,
                              hipStream_t stream)
{
    const float* x     = (const float*)d_in[0];
    const float* Wp    = (const float*)d_in[6];
    const float* bp    = (const float*)d_in[7];
    const float* Wself = (const float*)d_in[8];
    const float* Wnbr  = (const float*)d_in[9];
    const float* bconv = (const float*)d_in[10];
    const float* ln_g  = (const float*)d_in[11];
    const float* ln_b  = (const float*)d_in[12];
    float* out = (float*)d_out;

    char* p = (char*)d_ws;
    unsigned short* Wself_t = (unsigned short*)p; p += (size_t)12 * HH * HH * 2;  // 1.5 MiB
    unsigned short* Wnbr_t  = (unsigned short*)p; p += (size_t)12 * HH * HH * 2;  // 1.5 MiB
    unsigned short* Wp_t    = (unsigned short*)p; p += (size_t)HH * FDIM * 2;     // 0.5 MiB
    unsigned short* c0 = (unsigned short*)p; p += (size_t)R0 * HH * 2;            // 32 MiB
    unsigned short* c1 = (unsigned short*)p; p += (size_t)R1 * HH * 2;            // 16 MiB
    unsigned short* c2 = (unsigned short*)p; p += (size_t)R2 * HH * 2;            //  8 MiB
    unsigned short* c3 = (unsigned short*)p; p += (size_t)R3 * HH * 2;            //  4 MiB
    unsigned short* t1 = (unsigned short*)p; p += (size_t)R0 * HH * 2;            // 32 MiB
    unsigned short* t2 = (unsigned short*)p; p += (size_t)R0 * HH * 2;            // 32 MiB
    unsigned short* nb = (unsigned short*)p; p += (size_t)R0 * HH * 2;            // 32 MiB
    if (ws_size < (size_t)(p - (char*)d_ws)) return;

    // weight prep
    transpose_w<<<12 * 64, 256, 0, stream>>>(Wself, Wself_t, HH, 64);
    transpose_w<<<12 * 64, 256, 0, stream>>>(Wnbr,  Wnbr_t,  HH, 64);
    transpose_w<<<256, 256, 0, stream>>>(Wp, Wp_t, FDIM, 256);

    // 1. projection
    proj_gemm<<<dim3(2, R0 / 128), 256, 0, stream>>>(x, Wp_t, bp, c0);

    // 2. down path
    downsample_kernel<<<R1 / 8, 256, 0, stream>>>(c0, c1, R1);
    run_stage(0, R1, 2048, c1, true, true, t1, t2, nb, nullptr, Wself_t, Wnbr_t, bconv, ln_g, ln_b, stream);

    downsample_kernel<<<R2 / 8, 256, 0, stream>>>(c1, c2, R2);
    run_stage(1, R2, 1024, c2, true, true, t1, t2, nb, nullptr, Wself_t, Wnbr_t, bconv, ln_g, ln_b, stream);

    downsample_kernel<<<R3 / 8, 256, 0, stream>>>(c2, c3, R3);
    run_stage(2, R3, 512, c3, true, true, t1, t2, nb, nullptr, Wself_t, Wnbr_t, bconv, ln_g, ln_b, stream);

    // 3. up path
    upsample_add_kernel<<<R2 / 8, 256, 0, stream>>>(c2, c3, 512, 10, R2);
    run_stage(3, R2, 1024, c2, false, false, t1, t2, nb, nullptr, Wself_t, Wnbr_t, bconv, ln_g, ln_b, stream);

    upsample_add_kernel<<<R1 / 8, 256, 0, stream>>>(c1, c2, 1024, 11, R1);
    run_stage(4, R1, 2048, c1, false, false, t1, t2, nb, nullptr, Wself_t, Wnbr_t, bconv, ln_g, ln_b, stream);

    upsample_add_kernel<<<R0 / 8, 256, 0, stream>>>(c0, c1, 2048, 12, R0);
    run_stage(5, R0, 4096, c0, false, true, t1, t2, nb, out, Wself_t, Wnbr_t, bconv, ln_g, ln_b, stream);
}